// Round 7
// baseline (429.841 us; speedup 1.0000x reference)
//
#include <hip/hip_runtime.h>

// 8-point DCT-II matrix M[u][i] = c(u) * cos((2i+1) u pi / 16),
// c(0)=sqrt(1/8), c(u>0)=0.5.  K[u*8+v, i*8+j] = M[u][i]*M[v][j].
#define E8 0.35355339059327373f
#define C1 0.49039264020161522f
#define C3 0.41573480615127262f
#define C5 0.27778511650980114f
#define C7 0.09754516100806412f
#define D1 0.46193976625564337f
#define D3 0.19134171618254492f

static __device__ const float MK[8][8] = {
    { E8,  E8,  E8,  E8,  E8,  E8,  E8,  E8},
    { C1,  C3,  C5,  C7, -C7, -C5, -C3, -C1},
    { D1,  D3, -D3, -D1, -D1, -D3,  D3,  D1},
    { C3, -C7, -C1, -C5,  C5,  C1,  C7, -C3},
    { E8, -E8, -E8,  E8,  E8, -E8, -E8,  E8},
    { C5, -C1,  C7,  C3, -C3, -C7,  C1, -C5},
    { D3, -D1,  D1, -D3, -D3,  D1, -D1,  D3},
    { C7, -C5,  C3, -C1,  C1, -C3,  C5, -C7},
};

typedef float f4 __attribute__((ext_vector_type(4)));

__global__ __launch_bounds__(256) void dct_lds_kernel(
    const float* __restrict__ x,         // [16, 64, 256, 256]
    const float* __restrict__ backbone,  // [16, 64]
    const float* __restrict__ itw,       // [64]
    float* __restrict__ out)             // [16, 64, 256, 256]
{
    const int HW = 65536;
    const size_t CHW = (size_t)64 * HW;

    __shared__ float tile[64 * 256];     // [ch][px] tile, 64 KB
    __shared__ float s_sc[64];

    const int tid  = threadIdx.x;
    const int n    = blockIdx.x >> 8;            // 256 tiles per sample
    const int px0  = (blockIdx.x & 255) << 8;    // 256-pixel tile
    const int wave = tid >> 6;
    const int lane = tid & 63;

    if (tid < 64) s_sc[tid] = backbone[(n << 6) + tid] * itw[tid];

    // --- Stage: 64 channel segments, each 256 px = 1 KB contiguous,
    // one global_load_lds_dwordx4 per wave-instruction (1 KB/instr).
    // LDS dest is wave-uniform base + lane*16 (linear); global src is per-lane.
    const float* gbase = x + (size_t)n * CHW + px0 + lane * 4;
#pragma unroll
    for (int k = 0; k < 16; ++k) {
        const int ch = wave * 16 + k;
        __builtin_amdgcn_global_load_lds(
            (const __attribute__((address_space(1))) void*)(gbase + (size_t)ch * HW),
            (__attribute__((address_space(3))) void*)(&tile[ch * 256]),
            16, 0, 0);
    }
    __syncthreads();   // drains vmcnt (compiler emits vmcnt(0) before s_barrier)

    // --- Stage 1: per-pixel row transform t8[i][v] = sum_j M[v][j] x[i*8+j]
    // LDS reads: bank = tid % 32 -> conflict-free.
    float t8[8][8];
#pragma unroll
    for (int i = 0; i < 8; ++i) {
        float xr[8];
#pragma unroll
        for (int j = 0; j < 8; ++j) xr[j] = tile[(i * 8 + j) * 256 + tid];
#pragma unroll
        for (int v = 0; v < 8; ++v) {
            float a = MK[v][0] * xr[0];
#pragma unroll
            for (int j = 1; j < 8; ++j) a = fmaf(MK[v][j], xr[j], a);
            t8[i][v] = a;
        }
    }
    __syncthreads();   // all threads done reading x from the tile

    // --- Stage 2: y[u][v] = sum_i M[u][i] t8[i][v], written back into the tile
#pragma unroll
    for (int u = 0; u < 8; ++u) {
#pragma unroll
        for (int v = 0; v < 8; ++v) {
            float a = MK[u][0] * t8[0][v];
#pragma unroll
            for (int i = 1; i < 8; ++i) a = fmaf(MK[u][i], t8[i][v], a);
            tile[(u * 8 + v) * 256 + tid] = a;
        }
    }
    __syncthreads();

    // --- Cooperative stores: per channel, 64 lanes x 16 B = 1 KB contiguous.
    float* obase = out + (size_t)n * CHW + px0 + lane * 4;
#pragma unroll
    for (int k = 0; k < 16; ++k) {
        const int ch = wave * 16 + k;
        f4 r = *(const f4*)&tile[ch * 256 + lane * 4];
        const float s = s_sc[ch];
        r.x *= s; r.y *= s; r.z *= s; r.w *= s;
        *(f4*)(obase + (size_t)ch * HW) = r;
    }
}

extern "C" void kernel_launch(void* const* d_in, const int* in_sizes, int n_in,
                              void* d_out, int out_size, void* d_ws, size_t ws_size,
                              hipStream_t stream) {
    const float* x        = (const float*)d_in[0];
    const float* backbone = (const float*)d_in[1];
    const float* itw      = (const float*)d_in[2];
    float* out = (float*)d_out;

    // 16 samples * 256 tiles (256 px each) = 4096 blocks
    dct_lds_kernel<<<4096, 256, 0, stream>>>(x, backbone, itw, out);
}